// Round 5
// baseline (145.307 us; speedup 1.0000x reference)
//
#include <hip/hip_runtime.h>
#include <stdint.h>

typedef _Float16 half8  __attribute__((ext_vector_type(8)));
typedef float    f32x16 __attribute__((ext_vector_type(16)));
typedef uint32_t u32x4  __attribute__((ext_vector_type(4)));

#define NPIX 61504   // 16 * 62 * 62
#define LPB  3844    // 62*62
#define NOUT 64
#define NXPIX 2097152        // 16*32*64*64 input elems
#define WTAB_HALF8 20736     // 162 k-steps * 2 frags * 64 lanes
#define BFRAG_BYTES 332800   // weight table bytes, padded
#define WS_NEED ((size_t)BFRAG_BYTES + (size_t)NXPIX * 16)

// K enumeration (2880 = 288feat*8coef spline + 288 base; 162 steps of K=16):
//  spline steps 0..143: chunk ch=(i2*3+j2) (0..8), cc=st&15; k-elem (h,j) ->
//    channel c=2cc+h, coef j, feature f = 9c+3*i2+j2.
//  base steps 144..161: k-elem (h,j) -> feature f = stb*16+h*8+j, value relu(x).
// A-frag (weights, m=out): lane = h*32 + (o&31), comp j.   [32x32x16 A layout]
// B-frag (pixels,  n=px ): lane = h*32 + px_off, comp j.
// Weight table: frag fi = st*2 + (o>>5), half8 idx = fi*64 + h*32 + (o&31).

__global__ void prep_w(const float* __restrict__ bw,
                       const float* __restrict__ sw,
                       const float* __restrict__ sc,
                       half8* __restrict__ wt) {
  int t = blockIdx.x * 256 + threadIdx.x;      // 0..20735
  half8 v;
  int fi, h, o;
  if (t < 64 * 288) {                          // spline (o,f) pairs
    o = t / 288;
    int f = t - o * 288;
    float scale = sc[t];
    const float* p = sw + t * 8;
#pragma unroll
    for (int j = 0; j < 8; ++j) v[j] = (_Float16)(p[j] * scale);
    int c  = (f * 57) >> 9;                    // f/9  (f<512)
    int r  = f - c * 9;
    int i2 = (r * 11) >> 5;                    // r/3  (r<9)
    int j2 = r - i2 * 3;
    int st = (i2 * 3 + j2) * 16 + (c >> 1);
    h  = c & 1;
    fi = st * 2 + (o >> 5);
  } else {                                     // base: (o, 8-feature group)
    int t2 = t - 64 * 288;                     // 0..2303
    o = t2 / 36;
    int g8 = t2 - o * 36;
    const float* p = bw + o * 288 + g8 * 8;
#pragma unroll
    for (int j = 0; j < 8; ++j) v[j] = (_Float16)p[j];
    int stb = g8 >> 1;
    h  = g8 & 1;
    fi = (144 + stb) * 2 + (o >> 5);
  }
  wt[fi * 64 + h * 32 + (o & 31)] = v;
}

// ---------------- cubic B-spline basis: 8 slots, f16-packed ----------------
__device__ inline half8 bspline8(float xv) {
  float u = fmaf(xv, 2.5f, 5.5f);
  float fi = floorf(u);
  int i = (int)fi;
  float t = u - fi, s = 1.0f - t;
  float t2 = t * t, t3 = t2 * t;
  float s2 = s * s, s3 = s2 * s;
  float w3 = t3 * 0.16666667f;
  float w0 = s3 * 0.16666667f;
  float w1 = fmaf(0.5f, t3, -t2) + 0.66666667f;
  float w2 = fmaf(0.5f, s3, -s2) + 0.66666667f;
  uint32_t u01 = __builtin_bit_cast(uint32_t, __builtin_amdgcn_cvt_pkrtz(w0, w1));
  uint32_t u23 = __builtin_bit_cast(uint32_t, __builtin_amdgcn_cvt_pkrtz(w2, w3));
  uint64_t V = (uint64_t)u01 | ((uint64_t)u23 << 32);
  uint32_t vl = (uint32_t)(V << 16);
  u32x4 fr;
#pragma unroll
  for (int q = 0; q < 4; ++q) {
    int d = i - 2 * q;
    uint32_t rr = (uint32_t)(V >> ((48 - 16 * d) & 63));
    fr[q] = ((uint32_t)d <= 3u) ? rr : ((d == 4) ? vl : 0u);
  }
  return __builtin_bit_cast(half8, fr);
}

__global__ void precompute_basis(const float* __restrict__ x,
                                 half8* __restrict__ bsp) {
  int i = blockIdx.x * 256 + threadIdx.x;
  bsp[i] = bspline8(x[i]);
}

// --------- async weight staging: global -> LDS, lane-contiguous 16B ---------
__device__ inline void stage_chunk(const half8* __restrict__ s, half8* d,
                                   int nhalf8, int lane) {
  for (int it = 0; it < nhalf8; it += 64) {
#if __has_builtin(__builtin_amdgcn_global_load_lds)
    __builtin_amdgcn_global_load_lds(
        (const __attribute__((address_space(1))) uint32_t*)(s + it + lane),
        (__attribute__((address_space(3))) uint32_t*)(d + it),
        16, 0, 0);
#else
    d[it + lane] = s[it + lane];
#endif
  }
}

// ---------------- main v3: 32x32x16 MFMA, weights in LDS ----------------
// block = 128 thr = 2 waves; wave = 64 px (2 B-frags) x 64 outs (2 A-frags).
__global__ __launch_bounds__(128) void kan_main3(
    const float* __restrict__ x,
    const half8* __restrict__ bsp,
    const half8* __restrict__ wt,
    float* __restrict__ out) {
  __shared__ half8 smw[2][2048];               // 2 x 32 KB chunk buffers

  const int tid  = threadIdx.x;
  const int lane = tid & 63;
  const int wv   = tid >> 6;
  const int l31  = lane & 31;
  const int h    = lane >> 5;

  // XCD swizzle: contiguous 60-tile (~2 image) ranges per XCD
  int bid  = blockIdx.x;
  int tile = (bid < 480) ? ((bid & 7) * 60 + (bid >> 3)) : 480;
  const int pxw = tile * 128 + wv * 64;

  int xb[2];
#pragma unroll
  for (int np = 0; np < 2; ++np) {
    int p = pxw + np * 32 + l31;
    if (p > NPIX - 1) p = NPIX - 1;
    int b  = p / LPB;
    int l  = p - b * LPB;
    int ho = l / 62;
    int wo = l - ho * 62;
    xb[np] = b * 131072 + ho * 64 + wo;        // elem idx into x / bsp
  }

  f32x16 acc[2][2];                            // [mo][np]
#pragma unroll
  for (int mo = 0; mo < 2; ++mo)
#pragma unroll
    for (int np = 0; np < 2; ++np)
#pragma unroll
      for (int i = 0; i < 16; ++i) acc[mo][np][i] = 0.f;

  stage_chunk(wt + 0, &smw[0][0] + wv * 1024 - wv * 1024 + wv * 1024, 0, 0); // no-op guard (removed below)
  // real initial stage:
  stage_chunk(wt + wv * 1024, &smw[0][wv * 1024], 1024, lane);

  int buf = 0;
  for (int ch = 0; ch < 11; ++ch) {
    __syncthreads();                           // chunk `ch` staging complete
    if (ch < 10) {
      int nfr  = (ch < 9) ? 2048 : 256;        // next chunk: ch+1 (==10 -> 256)
      int half = ((ch + 1 < 10) ? 2048 : 256) >> 1;
      (void)nfr;
      stage_chunk(wt + (ch + 1) * 2048 + wv * half, &smw[buf ^ 1][wv * half],
                  half, lane);
    }
    const half8* wb = &smw[buf][0];

    if (ch < 9) {
      // spline chunk: fixed (i2,j2)=ch; c = 2*stl + h
      int i2 = (ch * 11) >> 5;                 // ch/3
      int j2 = ch - i2 * 3;
      const half8* bp0 = bsp + xb[0] + h * 4096 + i2 * 64 + j2;
      const half8* bp1 = bsp + xb[1] + h * 4096 + i2 * 64 + j2;
#pragma unroll
      for (int stl = 0; stl < 16; ++stl) {
        half8 b0 = bp0[stl * 8192];
        half8 b1 = bp1[stl * 8192];
        half8 a0 = wb[stl * 128 + lane];
        half8 a1 = wb[stl * 128 + 64 + lane];
        acc[0][0] = __builtin_amdgcn_mfma_f32_32x32x16_f16(a0, b0, acc[0][0], 0, 0, 0);
        acc[0][1] = __builtin_amdgcn_mfma_f32_32x32x16_f16(a0, b1, acc[0][1], 0, 0, 0);
        acc[1][0] = __builtin_amdgcn_mfma_f32_32x32x16_f16(a1, b0, acc[1][0], 0, 0, 0);
        acc[1][1] = __builtin_amdgcn_mfma_f32_32x32x16_f16(a1, b1, acc[1][1], 0, 0, 0);
      }
    } else {
      // base chunks: relu(x), features f = stb*16 + h*8 + j
      int nst = (ch == 9) ? 16 : 2;
      for (int stl = 0; stl < nst; ++stl) {
        int stb = (ch - 9) * 16 + stl;
        int fb0 = stb * 16 + h * 8;
        half8 bb[2];
#pragma unroll
        for (int np = 0; np < 2; ++np) {
          u32x4 pk;
#pragma unroll
          for (int jj = 0; jj < 4; ++jj) {
            float v0, v1;
            {
              int f = fb0 + jj * 2;
              int c = (f * 57) >> 9; int r = f - c * 9;
              int a = (r * 11) >> 5; int b2 = r - a * 3;
              v0 = fmaxf(x[xb[np] + c * 4096 + a * 64 + b2], 0.f);
            }
            {
              int f = fb0 + jj * 2 + 1;
              int c = (f * 57) >> 9; int r = f - c * 9;
              int a = (r * 11) >> 5; int b2 = r - a * 3;
              v1 = fmaxf(x[xb[np] + c * 4096 + a * 64 + b2], 0.f);
            }
            pk[jj] = __builtin_bit_cast(uint32_t, __builtin_amdgcn_cvt_pkrtz(v0, v1));
          }
          bb[np] = __builtin_bit_cast(half8, pk);
        }
        half8 a0 = wb[stl * 128 + lane];
        half8 a1 = wb[stl * 128 + 64 + lane];
        acc[0][0] = __builtin_amdgcn_mfma_f32_32x32x16_f16(a0, bb[0], acc[0][0], 0, 0, 0);
        acc[0][1] = __builtin_amdgcn_mfma_f32_32x32x16_f16(a0, bb[1], acc[0][1], 0, 0, 0);
        acc[1][0] = __builtin_amdgcn_mfma_f32_32x32x16_f16(a1, bb[0], acc[1][0], 0, 0, 0);
        acc[1][1] = __builtin_amdgcn_mfma_f32_32x32x16_f16(a1, bb[1], acc[1][1], 0, 0, 0);
      }
    }
    buf ^= 1;
  }

  // ---- epilogue: D row = out = (rg&3)+8*(rg>>2)+4*h, col = pixel = l31 ----
#pragma unroll
  for (int np = 0; np < 2; ++np) {
    int p = pxw + np * 32 + l31;
    bool ok = p < NPIX;
    int pc = ok ? p : NPIX - 1;
    int b = pc / LPB;
    int l = pc - b * LPB;
    float* ob = out + b * (NOUT * LPB) + l;
#pragma unroll
    for (int mo = 0; mo < 2; ++mo)
#pragma unroll
      for (int rg = 0; rg < 16; ++rg) {
        int o = mo * 32 + (rg & 3) + 8 * (rg >> 2) + 4 * h;
        if (ok) ob[o * LPB] = acc[mo][np][rg];
      }
  }
}

extern "C" void kernel_launch(void* const* d_in, const int* in_sizes, int n_in,
                              void* d_out, int out_size, void* d_ws, size_t ws_size,
                              hipStream_t stream) {
  const float* x  = (const float*)d_in[0];
  const float* bw = (const float*)d_in[1];  // (64, 288)
  const float* sw = (const float*)d_in[2];  // (64, 288, 8)
  const float* sc = (const float*)d_in[3];  // (64, 288)
  float* out = (float*)d_out;
  half8* wt  = (half8*)d_ws;                           // 331,776 B (padded 332,800)
  half8* bsp = (half8*)((char*)d_ws + BFRAG_BYTES);    // 33.5 MB basis table

  prep_w<<<81, 256, 0, stream>>>(bw, sw, sc, wt);
  precompute_basis<<<NXPIX / 256, 256, 0, stream>>>(x, bsp);
  kan_main3<<<481, 128, 0, stream>>>(x, bsp, wt, out);
}

// Round 6
// 132.928 us; speedup vs baseline: 1.0931x; 1.0931x over previous
//
#include <hip/hip_runtime.h>
#include <stdint.h>

typedef _Float16 half8  __attribute__((ext_vector_type(8)));
typedef float    f32x16 __attribute__((ext_vector_type(16)));
typedef uint32_t u32x4  __attribute__((ext_vector_type(4)));

#define NPIX 61504   // 16 * 62 * 62
#define LPB  3844    // 62*62
#define NOUT 64
#define NXPIX 2097152        // 16*32*64*64 input elems
#define BFRAG_BYTES 332800   // weight table bytes, padded
#define PF 4                 // prefetch depth (16 % PF == 0 required)

// K enumeration (162 steps of K=16):
//  spline steps 0..143: chunk ch=(i2*3+j2) (0..8), st=ch*16+cc; k-elem (h,j) ->
//    channel c=2cc+h, coef j, feature f = 9c+3*i2+j2.
//  base steps 144..161: k-elem (h,j) -> feature f = stb*16+h*8+j, value relu(x).
// A-frag (weights, m=out): lane = h*32 + (o&31), comp j.
// B-frag (pixels,  n=px ): lane = h*32 + px_off, comp j.
// Weight table: frag fi = st*2 + (o>>5), half8 idx = fi*64 + h*32 + (o&31).

// ---------------- cubic B-spline basis: 8 slots, f16-packed ----------------
__device__ inline half8 bspline8(float xv) {
  float u = fmaf(xv, 2.5f, 5.5f);
  float fi = floorf(u);
  int i = (int)fi;
  float t = u - fi, s = 1.0f - t;
  float t2 = t * t, t3 = t2 * t;
  float s2 = s * s, s3 = s2 * s;
  float w3 = t3 * 0.16666667f;
  float w0 = s3 * 0.16666667f;
  float w1 = fmaf(0.5f, t3, -t2) + 0.66666667f;
  float w2 = fmaf(0.5f, s3, -s2) + 0.66666667f;
  uint32_t u01 = __builtin_bit_cast(uint32_t, __builtin_amdgcn_cvt_pkrtz(w0, w1));
  uint32_t u23 = __builtin_bit_cast(uint32_t, __builtin_amdgcn_cvt_pkrtz(w2, w3));
  uint64_t V = (uint64_t)u01 | ((uint64_t)u23 << 32);
  uint32_t vl = (uint32_t)(V << 16);
  u32x4 fr;
#pragma unroll
  for (int q = 0; q < 4; ++q) {
    int d = i - 2 * q;
    uint32_t rr = (uint32_t)(V >> ((48 - 16 * d) & 63));
    fr[q] = ((uint32_t)d <= 3u) ? rr : ((d == 4) ? vl : 0u);
  }
  return __builtin_bit_cast(half8, fr);
}

// ------------- fused prep: basis table (blocks 0..8191) + weights -------------
__global__ void prep_all(const float* __restrict__ x,
                         const float* __restrict__ bw,
                         const float* __restrict__ sw,
                         const float* __restrict__ sc,
                         half8* __restrict__ bsp,
                         half8* __restrict__ wt) {
  int bid = blockIdx.x;
  if (bid < 8192) {                            // basis: one elem per thread
    int i = bid * 256 + threadIdx.x;
    bsp[i] = bspline8(x[i]);
    return;
  }
  int t = (bid - 8192) * 256 + threadIdx.x;    // 0..20735 weight frag-lanes
  half8 v;
  int fi, h, o;
  if (t < 64 * 288) {                          // spline (o,f) pairs
    o = t / 288;
    int f = t - o * 288;
    float scale = sc[t];
    const float* p = sw + t * 8;
#pragma unroll
    for (int j = 0; j < 8; ++j) v[j] = (_Float16)(p[j] * scale);
    int c  = (f * 57) >> 9;                    // f/9  (f<512)
    int r  = f - c * 9;
    int i2 = (r * 11) >> 5;                    // r/3  (r<9)
    int j2 = r - i2 * 3;
    int st = (i2 * 3 + j2) * 16 + (c >> 1);
    h  = c & 1;
    fi = st * 2 + (o >> 5);
  } else {                                     // base: (o, 8-feature group)
    int t2 = t - 64 * 288;                     // 0..2303
    o = t2 / 36;
    int g8 = t2 - o * 36;
    const float* p = bw + o * 288 + g8 * 8;
#pragma unroll
    for (int j = 0; j < 8; ++j) v[j] = (_Float16)p[j];
    int stb = g8 >> 1;
    h  = g8 & 1;
    fi = (144 + stb) * 2 + (o >> 5);
  }
  wt[fi * 64 + h * 32 + (o & 31)] = v;
}

// --------- async weight staging: global -> LDS, lane-contiguous 16B ---------
__device__ inline void stage(const half8* __restrict__ s, half8* d,
                             int n128, int tid) {
  int wv = tid >> 6, lane = tid & 63;
  for (int it = 0; it < n128; ++it) {
    int off = it * 128 + wv * 64;
#if __has_builtin(__builtin_amdgcn_global_load_lds)
    __builtin_amdgcn_global_load_lds(
        (const __attribute__((address_space(1))) uint32_t*)(s + off + lane),
        (__attribute__((address_space(3))) uint32_t*)(d + off),
        16, 0, 0);
#else
    d[off + lane] = s[off + lane];
#endif
  }
}

// ---------------- main v4: 32x32x16 MFMA, pipelined B prefetch ----------------
// block = 128 thr = 2 waves; wave = 64 px (2 B-frags) x 64 outs (2 A-frags).
__global__ __launch_bounds__(128, 2) void kan_main4(
    const float* __restrict__ x,
    const half8* __restrict__ bsp,
    const half8* __restrict__ wt,
    float* __restrict__ out) {
  __shared__ half8 smw[2][2304];               // 2 x 36 KB chunk buffers

  const int tid  = threadIdx.x;
  const int lane = tid & 63;
  const int wv   = tid >> 6;
  const int l31  = lane & 31;
  const int h    = lane >> 5;

  // XCD swizzle: contiguous 60-tile (~2 image) ranges per XCD
  int bid  = blockIdx.x;
  int tile = (bid < 480) ? ((bid & 7) * 60 + (bid >> 3)) : 480;
  const int pxw = tile * 128 + wv * 64;

  int xb[2];
#pragma unroll
  for (int np = 0; np < 2; ++np) {
    int p = pxw + np * 32 + l31;
    if (p > NPIX - 1) p = NPIX - 1;
    int b  = p / LPB;
    int l  = p - b * LPB;
    int ho = l / 62;
    int wo = l - ho * 62;
    xb[np] = b * 131072 + ho * 64 + wo;        // elem idx into x / bsp
  }

  f32x16 acc[2][2];                            // [mo][np]
#pragma unroll
  for (int mo = 0; mo < 2; ++mo)
#pragma unroll
    for (int np = 0; np < 2; ++np)
#pragma unroll
      for (int i = 0; i < 16; ++i) acc[mo][np][i] = 0.f;

  // initial weight chunk 0
  stage(wt, &smw[0][0], 16, tid);

  // B-operand ring: prefetch PF steps ahead, persists across chunk barriers
  const half8* pb0 = bsp + xb[0] + h * 4096;   // chunk 0: i2=0, j2=0
  const half8* pb1 = bsp + xb[1] + h * 4096;
  half8 b0r[PF], b1r[PF];
#pragma unroll
  for (int p = 0; p < PF; ++p) {
    b0r[p] = pb0[p * 8192];
    b1r[p] = pb1[p * 8192];
  }

  int buf = 0;
  for (int ch = 0; ch < 9; ++ch) {
    __syncthreads();                           // chunk `ch` staging complete
    if (ch < 8) stage(wt + (ch + 1) * 2048, &smw[buf ^ 1][0], 16, tid);
    else        stage(wt + 18432,           &smw[buf ^ 1][0], 18, tid);

    int i2n = ((ch + 1) * 11) >> 5;            // (ch+1)/3 ; ch=8 -> 3 (safe pad)
    int j2n = (ch + 1) - i2n * 3;
    const half8* nb0 = bsp + xb[0] + h * 4096 + i2n * 64 + j2n;
    const half8* nb1 = bsp + xb[1] + h * 4096 + i2n * 64 + j2n;
    const half8* wb = &smw[buf][0];

#pragma unroll
    for (int stl = 0; stl < 16; ++stl) {
      const int slot = stl & (PF - 1);
      half8 b0 = b0r[slot], b1 = b1r[slot];
      if (stl + PF < 16) {                     // refill for step stl+PF
        b0r[slot] = pb0[(stl + PF) * 8192];
        b1r[slot] = pb1[(stl + PF) * 8192];
      } else {                                 // first PF steps of next chunk
        b0r[slot] = nb0[(stl + PF - 16) * 8192];
        b1r[slot] = nb1[(stl + PF - 16) * 8192];
      }
      half8 a0 = wb[stl * 128 + lane];
      half8 a1 = wb[stl * 128 + 64 + lane];
      acc[0][0] = __builtin_amdgcn_mfma_f32_32x32x16_f16(a0, b0, acc[0][0], 0, 0, 0);
      acc[0][1] = __builtin_amdgcn_mfma_f32_32x32x16_f16(a0, b1, acc[0][1], 0, 0, 0);
      acc[1][0] = __builtin_amdgcn_mfma_f32_32x32x16_f16(a1, b0, acc[1][0], 0, 0, 0);
      acc[1][1] = __builtin_amdgcn_mfma_f32_32x32x16_f16(a1, b1, acc[1][1], 0, 0, 0);
    }
    pb0 = nb0;
    pb1 = nb1;
    buf ^= 1;
  }

  // ---- base section: 18 K-steps, weights fully staged in smw[buf] ----
  __syncthreads();
  {
    const half8* wb = &smw[buf][0];
#pragma unroll
    for (int stb = 0; stb < 18; ++stb) {
      int fb0 = stb * 16 + h * 8;
      half8 bb[2];
#pragma unroll
      for (int np = 0; np < 2; ++np) {
        u32x4 pk;
#pragma unroll
        for (int jj = 0; jj < 4; ++jj) {
          float v0, v1;
          {
            int f = fb0 + jj * 2;
            int c = (f * 57) >> 9; int r = f - c * 9;
            int a = (r * 11) >> 5; int b2 = r - a * 3;
            v0 = fmaxf(x[xb[np] + c * 4096 + a * 64 + b2], 0.f);
          }
          {
            int f = fb0 + jj * 2 + 1;
            int c = (f * 57) >> 9; int r = f - c * 9;
            int a = (r * 11) >> 5; int b2 = r - a * 3;
            v1 = fmaxf(x[xb[np] + c * 4096 + a * 64 + b2], 0.f);
          }
          pk[jj] = __builtin_bit_cast(uint32_t, __builtin_amdgcn_cvt_pkrtz(v0, v1));
        }
        bb[np] = __builtin_bit_cast(half8, pk);
      }
      half8 a0 = wb[stb * 128 + lane];
      half8 a1 = wb[stb * 128 + 64 + lane];
      acc[0][0] = __builtin_amdgcn_mfma_f32_32x32x16_f16(a0, bb[0], acc[0][0], 0, 0, 0);
      acc[0][1] = __builtin_amdgcn_mfma_f32_32x32x16_f16(a0, bb[1], acc[0][1], 0, 0, 0);
      acc[1][0] = __builtin_amdgcn_mfma_f32_32x32x16_f16(a1, bb[0], acc[1][0], 0, 0, 0);
      acc[1][1] = __builtin_amdgcn_mfma_f32_32x32x16_f16(a1, bb[1], acc[1][1], 0, 0, 0);
    }
  }

  // ---- epilogue: D row = out = (rg&3)+8*(rg>>2)+4*h, col = pixel = l31 ----
#pragma unroll
  for (int np = 0; np < 2; ++np) {
    int p = pxw + np * 32 + l31;
    bool ok = p < NPIX;
    int pc = ok ? p : NPIX - 1;
    int b = pc / LPB;
    int l = pc - b * LPB;
    float* ob = out + b * (NOUT * LPB) + l;
#pragma unroll
    for (int mo = 0; mo < 2; ++mo)
#pragma unroll
      for (int rg = 0; rg < 16; ++rg) {
        int o = mo * 32 + (rg & 3) + 8 * (rg >> 2) + 4 * h;
        if (ok) ob[o * LPB] = acc[mo][np][rg];
      }
  }
}

extern "C" void kernel_launch(void* const* d_in, const int* in_sizes, int n_in,
                              void* d_out, int out_size, void* d_ws, size_t ws_size,
                              hipStream_t stream) {
  const float* x  = (const float*)d_in[0];
  const float* bw = (const float*)d_in[1];  // (64, 288)
  const float* sw = (const float*)d_in[2];  // (64, 288, 8)
  const float* sc = (const float*)d_in[3];  // (64, 288)
  float* out = (float*)d_out;
  half8* wt  = (half8*)d_ws;                           // 331,776 B (padded)
  half8* bsp = (half8*)((char*)d_ws + BFRAG_BYTES);    // 33.5 MB basis table

  prep_all<<<8192 + 81, 256, 0, stream>>>(x, bw, sw, sc, bsp, wt);
  kan_main4<<<481, 128, 0, stream>>>(x, bsp, wt, out);
}

// Round 7
// 131.685 us; speedup vs baseline: 1.1034x; 1.0094x over previous
//
#include <hip/hip_runtime.h>
#include <stdint.h>

typedef _Float16 half8  __attribute__((ext_vector_type(8)));
typedef float    f32x16 __attribute__((ext_vector_type(16)));
typedef uint32_t u32x4  __attribute__((ext_vector_type(4)));

#define NPIX 61504   // 16 * 62 * 62
#define LPB  3844    // 62*62
#define NOUT 64
#define NXPIX 2097152        // 16*32*64*64 input elems
#define BFRAG_BYTES 332800   // weight table bytes, padded

// K enumeration (162 steps of K=16):
//  spline steps gs=0..143: sp=gs>>4 (=(i2,j2)), cc=gs&15; k-elem (h,j) ->
//    channel c=2cc+h, coef j, feature f = 9c+3*i2+j2.
//  base steps 144..161: k-elem (h,j) -> feature f = stb*16+h*8+j, value relu(x).
// A-frag (weights, m=out): lane = h*32 + (o&31), comp j.
// B-frag (pixels,  n=px ): lane = h*32 + px_off, comp j.
// Weight table: frag fi = st*2 + (o>>5), half8 idx = fi*64 + h*32 + (o&31).

// ---------------- cubic B-spline basis: 8 slots, f16-packed ----------------
__device__ inline half8 bspline8(float xv) {
  float u = fmaf(xv, 2.5f, 5.5f);
  float fi = floorf(u);
  int i = (int)fi;
  float t = u - fi, s = 1.0f - t;
  float t2 = t * t, t3 = t2 * t;
  float s2 = s * s, s3 = s2 * s;
  float w3 = t3 * 0.16666667f;
  float w0 = s3 * 0.16666667f;
  float w1 = fmaf(0.5f, t3, -t2) + 0.66666667f;
  float w2 = fmaf(0.5f, s3, -s2) + 0.66666667f;
  uint32_t u01 = __builtin_bit_cast(uint32_t, __builtin_amdgcn_cvt_pkrtz(w0, w1));
  uint32_t u23 = __builtin_bit_cast(uint32_t, __builtin_amdgcn_cvt_pkrtz(w2, w3));
  uint64_t V = (uint64_t)u01 | ((uint64_t)u23 << 32);
  uint32_t vl = (uint32_t)(V << 16);
  u32x4 fr;
#pragma unroll
  for (int q = 0; q < 4; ++q) {
    int d = i - 2 * q;
    uint32_t rr = (uint32_t)(V >> ((48 - 16 * d) & 63));
    fr[q] = ((uint32_t)d <= 3u) ? rr : ((d == 4) ? vl : 0u);
  }
  return __builtin_bit_cast(half8, fr);
}

// ------------- fused prep: basis table (blocks 0..8191) + weights -------------
__global__ void prep_all(const float* __restrict__ x,
                         const float* __restrict__ bw,
                         const float* __restrict__ sw,
                         const float* __restrict__ sc,
                         half8* __restrict__ bsp,
                         half8* __restrict__ wt) {
  int bid = blockIdx.x;
  if (bid < 8192) {                            // basis: one elem per thread
    int i = bid * 256 + threadIdx.x;
    bsp[i] = bspline8(x[i]);
    return;
  }
  int t = (bid - 8192) * 256 + threadIdx.x;    // 0..20735 weight frag-lanes
  half8 v;
  int fi, h, o;
  if (t < 64 * 288) {                          // spline (o,f) pairs
    o = t / 288;
    int f = t - o * 288;
    float scale = sc[t];
    const float* p = sw + t * 8;
#pragma unroll
    for (int j = 0; j < 8; ++j) v[j] = (_Float16)(p[j] * scale);
    int c  = (f * 57) >> 9;                    // f/9  (f<512)
    int r  = f - c * 9;
    int i2 = (r * 11) >> 5;                    // r/3  (r<9)
    int j2 = r - i2 * 3;
    int st = (i2 * 3 + j2) * 16 + (c >> 1);
    h  = c & 1;
    fi = st * 2 + (o >> 5);
  } else {                                     // base: (o, 8-feature group)
    int t2 = t - 64 * 288;                     // 0..2303
    o = t2 / 36;
    int g8 = t2 - o * 36;
    const float* p = bw + o * 288 + g8 * 8;
#pragma unroll
    for (int j = 0; j < 8; ++j) v[j] = (_Float16)p[j];
    int stb = g8 >> 1;
    h  = g8 & 1;
    fi = (144 + stb) * 2 + (o >> 5);
  }
  wt[fi * 64 + h * 32 + (o & 31)] = v;
}

// --------- async weight staging: global -> LDS, 256-thr, 16B/lane ---------
__device__ inline void stage256(const half8* __restrict__ s, half8* d,
                                int n, int tid) {
  int wv = tid >> 6, lane = tid & 63;
  for (int it = 0; it < n; it += 256) {
    int off = it + wv * 64;
#if __has_builtin(__builtin_amdgcn_global_load_lds)
    __builtin_amdgcn_global_load_lds(
        (const __attribute__((address_space(1))) uint32_t*)(s + off + lane),
        (__attribute__((address_space(3))) uint32_t*)(d + off),
        16, 0, 0);
#else
    d[off + lane] = s[off + lane];
#endif
  }
}

// ---------------- main v5: 4 waves x (32 px x 64 out), 8-step chunks ----------------
__global__ __launch_bounds__(256, 4) void kan_main5(
    const float* __restrict__ x,
    const half8* __restrict__ bsp,
    const half8* __restrict__ wt,
    float* __restrict__ out) {
  __shared__ half8 smw[2][1024];               // 2 x 16 KB chunk buffers

  const int tid  = threadIdx.x;
  const int lane = tid & 63;
  const int wv   = tid >> 6;
  const int l31  = lane & 31;
  const int h    = lane >> 5;

  // XCD swizzle: contiguous 60-tile (~2 image) ranges per XCD
  int bid  = blockIdx.x;
  int tile = (bid < 480) ? ((bid & 7) * 60 + (bid >> 3)) : 480;
  const int pxw = tile * 128 + wv * 32;

  int xb;
  {
    int p = pxw + l31;
    if (p > NPIX - 1) p = NPIX - 1;
    int b  = p / LPB;
    int l  = p - b * LPB;
    int ho = l / 62;
    int wo = l - ho * 62;
    xb = b * 131072 + ho * 64 + wo;            // elem idx into x / bsp
  }

  f32x16 acc[2];                               // [mo]
#pragma unroll
  for (int mo = 0; mo < 2; ++mo)
#pragma unroll
    for (int i = 0; i < 16; ++i) acc[mo][i] = 0.f;

  stage256(wt, &smw[0][0], 1024, tid);         // chunk 0

  int buf = 0;
  // ---- spline: 18 chunks x 8 K-steps ----
  for (int ch = 0; ch < 18; ++ch) {
    __syncthreads();                           // chunk `ch` staged
    if (ch < 17) stage256(wt + (ch + 1) * 1024, &smw[buf ^ 1][0], 1024, tid);
    else         stage256(wt + 18432,           &smw[buf ^ 1][0],  768, tid);

    int sp = ch >> 1;                          // spatial index, const per chunk
    int i2 = (sp * 11) >> 5;                   // sp/3
    int j2 = sp - i2 * 3;
    const half8* bp = bsp + xb + h * 4096 + i2 * 64 + j2 + (ch & 1) * (8 * 8192);
    const half8* wb = &smw[buf][0];

    half8 bv[8];
#pragma unroll
    for (int stl = 0; stl < 8; ++stl) bv[stl] = bp[stl * 8192];

#pragma unroll
    for (int stl = 0; stl < 8; ++stl) {
      half8 a0 = wb[stl * 128 + lane];
      half8 a1 = wb[stl * 128 + 64 + lane];
      acc[0] = __builtin_amdgcn_mfma_f32_32x32x16_f16(a0, bv[stl], acc[0], 0, 0, 0);
      acc[1] = __builtin_amdgcn_mfma_f32_32x32x16_f16(a1, bv[stl], acc[1], 0, 0, 0);
    }
    buf ^= 1;
  }

  // ---- base: 3 chunks x 6 K-steps, relu(x) B-operand ----
  for (int cb = 0; cb < 3; ++cb) {
    __syncthreads();
    if (cb < 2) stage256(wt + 18432 + (cb + 1) * 768, &smw[buf ^ 1][0], 768, tid);
    const half8* wb = &smw[buf][0];
#pragma unroll
    for (int stl = 0; stl < 6; ++stl) {
      int stb = cb * 6 + stl;
      int fb0 = stb * 16 + h * 8;
      u32x4 pk;
#pragma unroll
      for (int jj = 0; jj < 4; ++jj) {
        float v0, v1;
        {
          int f = fb0 + jj * 2;
          int c = (f * 57) >> 9; int r = f - c * 9;
          int a = (r * 11) >> 5; int b2 = r - a * 3;
          v0 = fmaxf(x[xb + c * 4096 + a * 64 + b2], 0.f);
        }
        {
          int f = fb0 + jj * 2 + 1;
          int c = (f * 57) >> 9; int r = f - c * 9;
          int a = (r * 11) >> 5; int b2 = r - a * 3;
          v1 = fmaxf(x[xb + c * 4096 + a * 64 + b2], 0.f);
        }
        pk[jj] = __builtin_bit_cast(uint32_t, __builtin_amdgcn_cvt_pkrtz(v0, v1));
      }
      half8 bb = __builtin_bit_cast(half8, pk);
      half8 a0 = wb[stl * 128 + lane];
      half8 a1 = wb[stl * 128 + 64 + lane];
      acc[0] = __builtin_amdgcn_mfma_f32_32x32x16_f16(a0, bb, acc[0], 0, 0, 0);
      acc[1] = __builtin_amdgcn_mfma_f32_32x32x16_f16(a1, bb, acc[1], 0, 0, 0);
    }
    buf ^= 1;
  }

  // ---- epilogue: D row = out = (rg&3)+8*(rg>>2)+4*h, col = pixel = l31 ----
  {
    int p = pxw + l31;
    bool ok = p < NPIX;
    int pc = ok ? p : NPIX - 1;
    int b = pc / LPB;
    int l = pc - b * LPB;
    float* ob = out + b * (NOUT * LPB) + l;
#pragma unroll
    for (int mo = 0; mo < 2; ++mo)
#pragma unroll
      for (int rg = 0; rg < 16; ++rg) {
        int o = mo * 32 + (rg & 3) + 8 * (rg >> 2) + 4 * h;
        if (ok) ob[o * LPB] = acc[mo][rg];
      }
  }
}

extern "C" void kernel_launch(void* const* d_in, const int* in_sizes, int n_in,
                              void* d_out, int out_size, void* d_ws, size_t ws_size,
                              hipStream_t stream) {
  const float* x  = (const float*)d_in[0];
  const float* bw = (const float*)d_in[1];  // (64, 288)
  const float* sw = (const float*)d_in[2];  // (64, 288, 8)
  const float* sc = (const float*)d_in[3];  // (64, 288)
  float* out = (float*)d_out;
  half8* wt  = (half8*)d_ws;                           // 331,776 B (padded)
  half8* bsp = (half8*)((char*)d_ws + BFRAG_BYTES);    // 33.5 MB basis table

  prep_all<<<8192 + 81, 256, 0, stream>>>(x, bw, sw, sc, bsp, wt);
  kan_main5<<<481, 256, 0, stream>>>(x, bsp, wt, out);
}